// Round 18
// baseline (815.115 us; speedup 1.0000x reference)
//
#include <hip/hip_runtime.h>

#define NF1 10
#define NCPF1 3
#define G1 145
#define G2 1506
#define KTOT 1536
#define NKT2 48
#define NS 20  // max distinct channels (slots) per 32-group k-tile, j-major order

typedef __attribute__((ext_vector_type(8))) short bf16x8;
typedef __attribute__((ext_vector_type(4))) float f32x4;

__device__ __forceinline__ ushort rne_bf16(float v) {
  union { float f; uint u; } a; a.f = v;
  return (ushort)((a.u + 0x7fffu + ((a.u >> 16) & 1u)) >> 16);
}
__device__ __forceinline__ float bf_to_f(ushort s) {
  union { uint u; float f; } a; a.u = ((uint)s) << 16;
  return a.f;
}
__device__ __forceinline__ void bsplit(float v, ushort& h, ushort& l) {
  union { float f; uint u; } a; a.f = v;
  uint hu = (a.u + 0x7fffu + ((a.u >> 16) & 1u)) >> 16;
  union { uint u; float f; } hf; hf.u = hu << 16;
  union { float f; uint u; } b2; b2.f = v - hf.f;
  h = (ushort)hu;
  l = (ushort)((b2.u + 0x7fffu + ((b2.u >> 16) & 1u)) >> 16);
}

// LDS-only barrier: drains lgkmcnt, leaves global loads in flight.
__device__ __forceinline__ void barrier_lds() {
  asm volatile("s_waitcnt lgkmcnt(0)" ::: "memory");
  __builtin_amdgcn_s_barrier();
}

// ---------------- stage-1 perm tables ----------------
__global__ void build_tables1(int* __restrict__ piv1, int* __restrict__ kk1, int* __restrict__ kj1) {
  int t = threadIdx.x;
  if (t < NF1) {
    int i = t;
    int base = 0;
    for (int ii = 0; ii < i; ++ii) base += (NF1 - ii) + (NCPF1 - 1) * (NF1 - 1 - ii);
    int count = base;
    for (int j = 0; j < NCPF1; ++j) {
      int k0 = (j == 0) ? i : (i + 1);
      for (int k = k0; k < NF1; ++k) {
        piv1[count] = i * NCPF1 + j;
        kk1[count] = k;
        kj1[count] = k * NCPF1 + j;
        ++count;
      }
    }
  }
}

// ---------------- stage-2 j-major order tables ----------------
// gPkS[newg] = pivslot | kjslot<<5 | filter<<10 ; ktsC[kt*NS+q] = chan | ic<<10
__global__ void build_perm2(int* __restrict__ gmap, ushort* __restrict__ gPkS, uint* __restrict__ ktsC) {
  int t = threadIdx.x;
  if (t >= NKT2) return;
  int chans[NS];
  int nch = 0;
  int pivs[32], kjs[32];
  int base = t * 32;
  for (int u = 0; u < 32; ++u) {
    int g = base + u;
    if (g >= G2) { pivs[u] = -1; kjs[u] = -1; gmap[g] = -1; gPkS[g] = 0; continue; }
    int i, j, k;
    if (g < 21) {
      j = 0; int r = g; i = 0; int len = 6;
      while (r >= len) { r -= len; ++i; len = 6 - i; }
      k = i + r;
    } else {
      int gp = g - 21; j = 1 + gp / 15; int r = gp % 15; i = 0; int len = 5;
      while (r >= len) { r -= len; ++i; len = 5 - i; }
      k = i + 1 + r;
    }
    pivs[u] = i * 100 + j; kjs[u] = k * 100 + j;
    int ob = (i == 0) ? 0 : (i == 1) ? 501 : (i == 2) ? 902 : (i == 3) ? 1203 : (i == 4) ? 1404 : 1505;
    int old;
    if (j == 0) old = ob + (k - i);
    else old = ob + (6 - i) + (j - 1) * (5 - i) + (k - i - 1);
    gmap[g] = old;
  }
  for (int u = 0; u < 32; ++u) {
    int g = base + u;
    if (g >= G2) continue;
    int ps = -1, ks2 = -1;
    for (int q = 0; q < nch; ++q) {
      if (chans[q] == pivs[u]) ps = q;
      if (chans[q] == kjs[u]) ks2 = q;
    }
    if (ps < 0) { ps = nch; chans[nch++] = pivs[u]; }
    if (ks2 < 0) { ks2 = nch; chans[nch++] = kjs[u]; }
    int f = kjs[u] / 100;
    gPkS[g] = (ushort)(ps | (ks2 << 5) | (f << 10));
  }
  for (int q = 0; q < NS; ++q) {
    int ch = (q < nch) ? chans[q] : 0;
    ktsC[t * NS + q] = (uint)ch | ((uint)(ch / 6) << 10);
  }
}

// split + column-permute pw2 weights into bf16 hi/lo planes [320][1536]
__global__ __launch_bounds__(256) void prep_w2(const float* __restrict__ pw2w, const int* __restrict__ gmap,
                                               ushort* __restrict__ whi, ushort* __restrict__ wlo) {
  int idx = blockIdx.x * 256 + threadIdx.x;
  if (idx >= 320 * KTOT) return;
  int oc = idx / KTOT, k = idx % KTOT;
  int old = gmap[k];
  float v = (oc < 300 && old >= 0) ? pw2w[oc * G2 + old] : 0.f;
  ushort h, l;
  bsplit(v, h, l);
  whi[idx] = h;
  wlo[idx] = l;
}

// split pw1 weights -> bf16 hi/lo [128][160]
__global__ __launch_bounds__(256) void prep_w1(const float* __restrict__ pw1w, ushort* __restrict__ p1h,
                                               ushort* __restrict__ p1l) {
  int idx = blockIdx.x * 256 + threadIdx.x;
  if (idx >= 128 * 160) return;
  int oc = idx / 160, k = idx % 160;
  float v = (oc < 100 && k < G1) ? pw1w[oc * G1 + k] : 0.f;
  ushort h, l;
  bsplit(v, h, l);
  p1h[idx] = h;
  p1l[idx] = l;
}

// pack dw2 weights [600][12]
__global__ __launch_bounds__(256) void prep_dw2(const float* __restrict__ dw2w, const float* __restrict__ dw2b,
                                                float* __restrict__ dw2p) {
  int c = blockIdx.x * 256 + threadIdx.x;
  if (c >= 600) return;
  for (int q = 0; q < 9; ++q) dw2p[c * 12 + q] = dw2w[c * 9 + q];
  dw2p[c * 12 + 9] = dw2b[c];
  dw2p[c * 12 + 10] = 0.f;
  dw2p[c * 12 + 11] = 0.f;
}

// combined filter-sum stencil: wcomb[6][18][9], bcomb[6]
__global__ void prep_wcomb(const float* __restrict__ dw2w, const float* __restrict__ dw2b,
                           float* __restrict__ wcomb, float* __restrict__ bcomb) {
  int idx = threadIdx.x + blockIdx.x * 256;
  if (idx < 6 * 18 * 9) {
    int f = idx / 162, s = (idx % 162) / 9, tap = idx % 9;
    int ic = (f * 100) / 6 + s;
    int clo = f * 100, chi = f * 100 + 100;
    int ilo = ic * 6, ihi = ic * 6 + 6;
    int lo = clo > ilo ? clo : ilo;
    int hi = chi < ihi ? chi : ihi;
    float sacc = 0.f;
    for (int c = lo; c < hi; ++c) sacc += dw2w[c * 9 + tap];
    wcomb[idx] = sacc;
  }
  if (idx < 6) {
    float sacc = 0.f;
    for (int m = 0; m < 100; ++m) sacc += dw2b[idx * 100 + m];
    bcomb[idx] = sacc;
  }
}

// ---------------- stage 1 (proven): dwconv1 + perm1 + pw1 via MFMA + in-lane pool ----------------
__global__ __launch_bounds__(256) void stage1f(const float* __restrict__ x, const float* __restrict__ dw1w,
                                               const float* __restrict__ dw1b, const ushort* __restrict__ p1h,
                                               const ushort* __restrict__ p1l, const float* __restrict__ pw1b,
                                               const int* __restrict__ piv, const int* __restrict__ kk,
                                               const int* __restrict__ kj, ushort* __restrict__ h1) {
  __shared__ float xs[3][4][34];
  __shared__ float ys[30][64];
  __shared__ float Ss[NF1][64];
  __shared__ ushort g[64][168];
  __shared__ uint tbl[G1];

  int b = blockIdx.x >> 4;
  int oh = blockIdx.x & 15;
  int t = threadIdx.x;
  int lane = t & 63, wave = t >> 6;
  int lrow = lane & 15, lkk = lane >> 4;

  if (t < G1) tbl[t] = (uint)piv[t] | ((uint)kj[t] << 8) | ((uint)kk[t] << 16);
  for (int idx = t; idx < 3 * 4 * 34; idx += 256) {
    int c = idx / 136, rem = idx % 136;
    int r = rem / 34, cc = rem % 34;
    int row = 2 * oh - 1 + r, col = cc - 1;
    float v = 0.f;
    if (row >= 0 && row < 32 && col >= 0 && col < 32) v = x[(((size_t)b * 3 + c) * 32 + row) * 32 + col];
    xs[c][r][cc] = v;
  }
  __syncthreads();
  for (int idx = t; idx < 30 * 64; idx += 256) {
    int c = idx >> 6, p = idx & 63;
    int rr = p >> 5, w = p & 31;
    int ic = c / 10;
    float acc = dw1b[c];
#pragma unroll
    for (int kh = 0; kh < 3; ++kh)
#pragma unroll
      for (int kw = 0; kw < 3; ++kw) acc += xs[ic][rr + kh][w + kw] * dw1w[c * 9 + kh * 3 + kw];
    ys[c][p] = acc;
  }
  __syncthreads();
  for (int idx = t; idx < NF1 * 64; idx += 256) {
    int f = idx >> 6, p = idx & 63;
    Ss[f][p] = ys[3 * f][p] + ys[3 * f + 1][p] + ys[3 * f + 2][p];
  }
  __syncthreads();
  {
    int n = t >> 2, qd = t & 3;
    int sub = n >> 4, ow = n & 15;
    int px = 32 * (sub >> 1) + 2 * ow + (sub & 1);
#pragma unroll
    for (int pass = 0; pass < 10; ++pass) {
      int k0 = pass * 16 + qd * 4;
      union { ushort us[4]; unsigned long long v; } pv;
#pragma unroll
      for (int c = 0; c < 4; ++c) {
        int k = k0 + c;
        float val = 0.f;
        if (k < G1) {
          uint tb = tbl[k];
          val = fmaxf(ys[(tb & 255)][px] + Ss[(tb >> 16)][px] - ys[((tb >> 8) & 255)][px], 0.f);
        }
        pv.us[c] = rne_bf16(val);
      }
      *(unsigned long long*)&g[n][k0] = pv.v;
    }
  }
  __syncthreads();
  f32x4 acc[2][4];
#pragma unroll
  for (int mt = 0; mt < 2; ++mt)
#pragma unroll
    for (int nt = 0; nt < 4; ++nt) acc[mt][nt] = (f32x4){0.f, 0.f, 0.f, 0.f};
#pragma unroll
  for (int ks = 0; ks < 5; ++ks) {
    int koff = ks * 32 + lkk * 8;
    bf16x8 Bh[4];
#pragma unroll
    for (int nt = 0; nt < 4; ++nt) Bh[nt] = *(const bf16x8*)&g[nt * 16 + lrow][koff];
#pragma unroll
    for (int mt = 0; mt < 2; ++mt) {
      int row = wave * 32 + mt * 16 + lrow;
      bf16x8 Ah = *(const bf16x8*)(p1h + row * 160 + koff);
      bf16x8 Al = *(const bf16x8*)(p1l + row * 160 + koff);
#pragma unroll
      for (int nt = 0; nt < 4; ++nt) {
        f32x4 c = acc[mt][nt];
        c = __builtin_amdgcn_mfma_f32_16x16x32_bf16(Ah, Bh[nt], c, 0, 0, 0);
        c = __builtin_amdgcn_mfma_f32_16x16x32_bf16(Al, Bh[nt], c, 0, 0, 0);
        acc[mt][nt] = c;
      }
    }
  }
#pragma unroll
  for (int mt = 0; mt < 2; ++mt) {
#pragma unroll
    for (int r = 0; r < 4; ++r) {
      int oc = wave * 32 + mt * 16 + lkk * 4 + r;
      if (oc < 100) {
        float v = fmaxf(fmaxf(acc[mt][0][r], acc[mt][1][r]), fmaxf(acc[mt][2][r], acc[mt][3][r]));
        float h = fmaxf(v + pw1b[oc], 0.f);
        h1[((size_t)b * 100 + oc) * 256 + oh * 16 + lrow] = rne_bf16(h);
      }
    }
  }
}

// ---------------- stage 2 v18: N=128 half-image tiles (1000 blocks, phases halved) ----------------
// block = (b, half q). 8 waves: 4 producers (C1 slots + C2), 4 consumers (acc[5][8]).
// LDS: h1s[100][10][20]u16 @0 (40000) | y2c[2][20][130]f32 @40000 (20800) | G 2x128x80B @60800 (20480)
//      Slp[6][132]f32 @81280 (3168) | gPk u16[1536] @84448 (3072) | kts u32[960] @87520 (3840) = 91360
__global__ __launch_bounds__(512, 2) void stage2f(
    const ushort* __restrict__ h1, const ushort* __restrict__ whi, const ushort* __restrict__ wlo,
    const float* __restrict__ dw2p, const float* __restrict__ wcomb, const float* __restrict__ bcomb,
    const float* __restrict__ pw2b, const ushort* __restrict__ gPkS, const uint* __restrict__ ktsC,
    ushort* __restrict__ h2) {
  extern __shared__ char sm[];
  ushort* h1s = (ushort*)sm;
  float* y2c = (float*)(sm + 40000);
  char* Ghb = sm + 60800;
  float* Slp = (float*)(sm + 81280);
  ushort* gPk = (ushort*)(sm + 84448);
  uint* kts = (uint*)(sm + 87520);

  int blk = blockIdx.x;
  int b = blk >> 1, q = blk & 1;  // half q: output rows 8q..8q+7 (pre-pool)
  int t = threadIdx.x;
  int lane = t & 63, wave = t >> 6;
  int lrow = lane & 15, lkk = lane >> 4;

  for (int i = t; i < 768; i += 512) ((uint*)gPk)[i] = ((const uint*)gPkS)[i];
  for (int i = t; i < NKT2 * NS; i += 512) kts[i] = ktsC[i];
  for (int i = t; i < 10000; i += 512) ((uint*)h1s)[i] = 0u;
  __syncthreads();
  const ushort* hb = h1 + (size_t)b * 25600;
  for (int i = t; i < 1000; i += 512) {
    int ic = i / 10, rr = i % 10;
    int hr = 8 * q - 1 + rr;
    if (hr >= 0 && hr < 16) {
      const ushort* src = hb + ic * 256 + hr * 16;
      ushort* dst = &h1s[(ic * 10 + rr) * 20 + 1];
#pragma unroll
      for (int c2 = 0; c2 < 16; ++c2) dst[c2] = src[c2];
    }
  }
  __syncthreads();
  // filter sums S (f32) for this half's 128 pixels
  for (int i = t; i < 6 * 128; i += 512) {
    int f = i >> 7, p = i & 127;
    int r = p >> 4, w = p & 15;
    int iclo = (f * 100) / 6;
    float s = bcomb[f];
    for (int ss2 = 0; ss2 < 18; ++ss2) {
      int ic = iclo + ss2;
      if (ic > 99) ic = 99;
      const float* wv = wcomb + (f * 18 + ss2) * 9;
#pragma unroll
      for (int dh = 0; dh < 3; ++dh)
#pragma unroll
        for (int dw = 0; dw < 3; ++dw)
          s += wv[dh * 3 + dw] * bf_to_f(h1s[(ic * 10 + r + dh) * 20 + w + dw]);
    }
    Slp[f * 132 + p] = s;
  }
  __syncthreads();

  if (wave < 4) {
    // ===== PRODUCERS (t<256): C1 slots (tile s) + C2 (tile s-1, pk prefetched) =====
    int n = t & 127, kg = t >> 7;  // C2: pixel n, k-group kg (16 k's)
    uint4 pkN0 = {0, 0, 0, 0}, pkN1 = {0, 0, 0, 0};
    for (int s = 0; s <= NKT2 + 1; ++s) {
      uint4 pkC0 = pkN0, pkC1 = pkN1;
      if (s < NKT2) {
        pkN0 = *(const uint4*)&gPk[s * 32 + kg * 16];
        pkN1 = *(const uint4*)&gPk[s * 32 + kg * 16 + 8];
      }
      // C2: G build for tile s-1
      if (s >= 1 && s <= NKT2) {
        int bc = (s - 1) & 1;
        char* gb = Ghb + bc * 10240;
#pragma unroll
        for (int h = 0; h < 2; ++h) {
          uint w4x = h ? pkC1.x : pkC0.x, w4y = h ? pkC1.y : pkC0.y;
          uint w4z = h ? pkC1.z : pkC0.z, w4w = h ? pkC1.w : pkC0.w;
          uint w4[4] = {w4x, w4y, w4z, w4w};
          union { ushort us[8]; bf16x8 v; } ph;
#pragma unroll
          for (int c = 0; c < 8; ++c) {
            uint pk = (w4[c >> 1] >> ((c & 1) * 16)) & 0xffffu;
            int ps = pk & 31, ks = (pk >> 5) & 31, f = (pk >> 10) & 7;
            float v = fmaxf(y2c[bc * 2600 + ps * 130 + n] + Slp[f * 132 + n] -
                            y2c[bc * 2600 + ks * 130 + n], 0.f);
            ph.us[c] = rne_bf16(v);
          }
          int oct = kg * 2 + h;
          uint off = (uint)n * 80u + (uint)((oct ^ (n & 3)) * 16);
          *(bf16x8*)(gb + off) = ph.v;
        }
      }
      // C1: dwconv2 slots for tile s (320 tasks: 20 slots x 8 rows x 2 halves)
      if (s < NKT2) {
#pragma unroll
        for (int pass = 0; pass < 2; ++pass) {
          int task = pass ? (256 + t) : t;
          if (pass == 0 || t < 64) {
            int slot = task >> 4, rem = task & 15, r = rem >> 1, half = rem & 1;
            uint ci = kts[s * NS + slot];
            int chan = ci & 1023, ic = (ci >> 10) & 127;
            const float4* wp4 = (const float4*)(dw2p + chan * 12);
            float4 wa = wp4[0], wb4 = wp4[1], wc4 = wp4[2];
            int w0 = half * 8;
            float fr[3][10];
#pragma unroll
            for (int dr = 0; dr < 3; ++dr)
#pragma unroll
              for (int cc = 0; cc < 10; ++cc)
                fr[dr][cc] = bf_to_f(h1s[(ic * 10 + r + dr) * 20 + w0 + cc]);
            float* dst = &y2c[(s & 1) * 2600 + slot * 130 + r * 16 + w0];
#pragma unroll
            for (int w = 0; w < 8; ++w) {
              float sa = wc4.y;
              sa += fr[0][w] * wa.x + fr[0][w + 1] * wa.y + fr[0][w + 2] * wa.z;
              sa += fr[1][w] * wa.w + fr[1][w + 1] * wb4.x + fr[1][w + 2] * wb4.y;
              sa += fr[2][w] * wb4.z + fr[2][w + 1] * wb4.w + fr[2][w + 2] * wc4.x;
              dst[w] = sa;
            }
          }
        }
      }
      barrier_lds();
    }
  } else {
    // ===== CONSUMERS: MFMA tile s-2 (A regs from phase s-1, B in-phase from LDS) =====
    int cw = wave - 4;  // 0..3 -> 80 oc rows each
    f32x4 acc[5][8];
#pragma unroll
    for (int mt = 0; mt < 5; ++mt)
#pragma unroll
      for (int nt = 0; nt < 8; ++nt) acc[mt][nt] = (f32x4){0.f, 0.f, 0.f, 0.f};
    bf16x8 Ah[5], Al[5];

    for (int s = 0; s <= NKT2 + 1; ++s) {
      if (s >= 2) {
        int bm = (s - 2) & 1;
        const char* gb = Ghb + bm * 10240;
        __builtin_amdgcn_s_setprio(1);
#pragma unroll
        for (int nt = 0; nt < 8; ++nt) {
          int n2 = nt * 16 + lrow;
          uint off = (uint)n2 * 80u + (uint)((lkk ^ (n2 & 3)) * 16);
          bf16x8 Bh = *(const bf16x8*)(gb + off);
#pragma unroll
          for (int mt = 0; mt < 5; ++mt) {
            f32x4 c = acc[mt][nt];
            c = __builtin_amdgcn_mfma_f32_16x16x32_bf16(Ah[mt], Bh, c, 0, 0, 0);
            c = __builtin_amdgcn_mfma_f32_16x16x32_bf16(Al[mt], Bh, c, 0, 0, 0);
            acc[mt][nt] = c;
          }
        }
        __builtin_amdgcn_s_setprio(0);
      }
      int ka = s - 1;
      if (ka >= 0 && ka < NKT2) {
        const size_t wof = (size_t)(cw * 80 + lrow) * KTOT + (size_t)ka * 32 + (size_t)lkk * 8;
#pragma unroll
        for (int mt = 0; mt < 5; ++mt) {
          Ah[mt] = *(const bf16x8*)(whi + wof + (size_t)mt * 16 * KTOT);
          Al[mt] = *(const bf16x8*)(wlo + wof + (size_t)mt * 16 * KTOT);
        }
      }
      barrier_lds();
    }

    // epilogue: pool rows (nt pairs) + cols (lane shuffle), bias, relu, bf16 store
#pragma unroll
    for (int mt = 0; mt < 5; ++mt) {
      int ocb = cw * 80 + mt * 16 + lkk * 4;
#pragma unroll
      for (int p = 0; p < 4; ++p) {
#pragma unroll
        for (int r = 0; r < 4; ++r) {
          float v = fmaxf(acc[mt][2 * p][r], acc[mt][2 * p + 1][r]);
          float v2 = fmaxf(v, __shfl_xor(v, 1));
          int oc = ocb + r;
          if ((lane & 1) == 0 && oc < 300) {
            float o = fmaxf(v2 + pw2b[oc], 0.f);
            h2[((size_t)b * 300 + oc) * 64 + (q * 4 + p) * 8 + (lrow >> 1)] = rne_bf16(o);
          }
        }
      }
    }
  }
}

// ---------------- FC (folded fc2@fc1) ----------------
__global__ __launch_bounds__(256) void fold_fc(const float* __restrict__ fc1w, const float* __restrict__ fc2w,
                                               float* __restrict__ combW) {
  int idx = blockIdx.x * 256 + threadIdx.x;
  if (idx >= 10 * 19200) return;
  int o = idx / 19200, c = idx % 19200;
  float s = 0.f;
  for (int m = 0; m < 120; ++m) s += fc2w[o * 120 + m] * fc1w[m * 19200 + c];
  combW[idx] = s;
}

__global__ void fold_b(const float* __restrict__ fc1b, const float* __restrict__ fc2w,
                       const float* __restrict__ fc2b, float* __restrict__ combB) {
  int o = threadIdx.x;
  if (o < 10) {
    float s = fc2b[o];
    for (int m = 0; m < 120; ++m) s += fc2w[o * 120 + m] * fc1b[m];
    combB[o] = s;
  }
}

__global__ __launch_bounds__(256) void fc_out(const ushort* __restrict__ h2, const float* __restrict__ combW,
                                              const float* __restrict__ combB, float* __restrict__ out, int b0) {
  int b = blockIdx.x / 10, o = blockIdx.x % 10;
  const ushort* hp = h2 + (size_t)b * 19200;
  const float* wp = combW + (size_t)o * 19200;
  float s = 0.f;
  for (int idx = threadIdx.x; idx < 2400; idx += 256) {
    bf16x8 hv = *(const bf16x8*)(hp + idx * 8);
    float4 w0 = *(const float4*)(wp + idx * 8);
    float4 w1 = *(const float4*)(wp + idx * 8 + 4);
    s += bf_to_f((ushort)hv[0]) * w0.x + bf_to_f((ushort)hv[1]) * w0.y;
    s += bf_to_f((ushort)hv[2]) * w0.z + bf_to_f((ushort)hv[3]) * w0.w;
    s += bf_to_f((ushort)hv[4]) * w1.x + bf_to_f((ushort)hv[5]) * w1.y;
    s += bf_to_f((ushort)hv[6]) * w1.z + bf_to_f((ushort)hv[7]) * w1.w;
  }
  __shared__ float red[256];
  red[threadIdx.x] = s;
  __syncthreads();
  for (int stride = 128; stride > 0; stride >>= 1) {
    if (threadIdx.x < stride) red[threadIdx.x] += red[threadIdx.x + stride];
    __syncthreads();
  }
  if (threadIdx.x == 0) out[(size_t)(b0 + b) * 10 + o] = red[0] + combB[o];
}

extern "C" void kernel_launch(void* const* d_in, const int* in_sizes, int n_in,
                              void* d_out, int out_size, void* d_ws, size_t ws_size,
                              hipStream_t stream) {
  const float* x = (const float*)d_in[0];
  const float* dw1w = (const float*)d_in[1];
  const float* dw1b = (const float*)d_in[2];
  const float* pw1w = (const float*)d_in[3];
  const float* pw1b = (const float*)d_in[4];
  const float* dw2w = (const float*)d_in[5];
  const float* dw2b = (const float*)d_in[6];
  const float* pw2w = (const float*)d_in[7];
  const float* pw2b = (const float*)d_in[8];
  const float* fc1w = (const float*)d_in[9];
  const float* fc1b = (const float*)d_in[10];
  const float* fc2w = (const float*)d_in[11];
  const float* fc2b = (const float*)d_in[12];
  float* out = (float*)d_out;

  char* ws = (char*)d_ws;
  size_t off = 0;
  auto alloc = [&](size_t bytes) -> void* {
    off = (off + 255) & ~(size_t)255;
    void* p = ws + off;
    off += bytes;
    return p;
  };
  int* piv1 = (int*)alloc(G1 * 4);
  int* kk1 = (int*)alloc(G1 * 4);
  int* kj1 = (int*)alloc(G1 * 4);
  int* gmap = (int*)alloc(KTOT * 4);
  ushort* gPkS = (ushort*)alloc(KTOT * 2);
  uint* ktsC = (uint*)alloc(NKT2 * NS * 4);
  float* combW = (float*)alloc((size_t)10 * 19200 * 4);
  float* combB = (float*)alloc(16 * 4);
  ushort* whi = (ushort*)alloc((size_t)320 * KTOT * 2);
  ushort* wlo = (ushort*)alloc((size_t)320 * KTOT * 2);
  ushort* p1h = (ushort*)alloc((size_t)128 * 160 * 2);
  ushort* p1l = (ushort*)alloc((size_t)128 * 160 * 2);
  float* dw2p = (float*)alloc((size_t)600 * 12 * 4);
  float* wcombp = (float*)alloc((size_t)6 * 18 * 9 * 4);
  float* bcombp = (float*)alloc(8 * 4);
  size_t static_end = (off + 255) & ~(size_t)255;

  size_t per_img = 51200 + 38400;
  long long avail = (long long)ws_size - (long long)static_end - 4096;
  int CB = 1;
  if (avail > 0) {
    long long c = avail / (long long)(per_img + 512);
    if (c > 500) c = 500;
    if (c < 1) c = 1;
    CB = (int)c;
  }
  ushort* h1 = (ushort*)alloc((size_t)CB * 25600 * 2);
  ushort* h2 = (ushort*)alloc((size_t)CB * 19200 * 2);

  const uint SMEM2 = 91360;
  hipFuncSetAttribute((const void*)stage2f, hipFuncAttributeMaxDynamicSharedMemorySize, (int)SMEM2);

  build_tables1<<<1, 64, 0, stream>>>(piv1, kk1, kj1);
  build_perm2<<<1, 64, 0, stream>>>(gmap, gPkS, ktsC);
  prep_dw2<<<3, 256, 0, stream>>>(dw2w, dw2b, dw2p);
  prep_wcomb<<<4, 256, 0, stream>>>(dw2w, dw2b, wcombp, bcombp);
  prep_w2<<<(320 * KTOT + 255) / 256, 256, 0, stream>>>(pw2w, gmap, whi, wlo);
  prep_w1<<<(128 * 160 + 255) / 256, 256, 0, stream>>>(pw1w, p1h, p1l);
  fold_fc<<<(10 * 19200 + 255) / 256, 256, 0, stream>>>(fc1w, fc2w, combW);
  fold_b<<<1, 64, 0, stream>>>(fc1b, fc2w, fc2b, combB);

  for (int b0 = 0; b0 < 500; b0 += CB) {
    int nb = 500 - b0 < CB ? 500 - b0 : CB;
    stage1f<<<nb * 16, 256, 0, stream>>>(x + (size_t)b0 * 3 * 1024, dw1w, dw1b, p1h, p1l, pw1b,
                                         piv1, kk1, kj1, h1);
    stage2f<<<nb * 2, 512, SMEM2, stream>>>(h1, whi, wlo, dw2p, wcombp, bcombp, pw2b,
                                            gPkS, ktsC, h2);
    fc_out<<<nb * 10, 256, 0, stream>>>(h2, combW, combB, out, b0);
  }
}

// Round 19
// 773.922 us; speedup vs baseline: 1.0532x; 1.0532x over previous
//
#include <hip/hip_runtime.h>

#define NF1 10
#define NCPF1 3
#define G1 145
#define G2 1506
#define KTOT 1536
#define NKT2 48
#define NS 20  // max distinct channels (slots) per 32-group k-tile, j-major order

typedef __attribute__((ext_vector_type(8))) short bf16x8;
typedef __attribute__((ext_vector_type(4))) float f32x4;

__device__ __forceinline__ ushort rne_bf16(float v) {
  union { float f; uint u; } a; a.f = v;
  return (ushort)((a.u + 0x7fffu + ((a.u >> 16) & 1u)) >> 16);
}
__device__ __forceinline__ float bf_to_f(ushort s) {
  union { uint u; float f; } a; a.u = ((uint)s) << 16;
  return a.f;
}
__device__ __forceinline__ void bsplit(float v, ushort& h, ushort& l) {
  union { float f; uint u; } a; a.f = v;
  uint hu = (a.u + 0x7fffu + ((a.u >> 16) & 1u)) >> 16;
  union { uint u; float f; } hf; hf.u = hu << 16;
  union { float f; uint u; } b2; b2.f = v - hf.f;
  h = (ushort)hu;
  l = (ushort)((b2.u + 0x7fffu + ((b2.u >> 16) & 1u)) >> 16);
}

// LDS-only barrier: drains lgkmcnt, leaves global loads in flight.
__device__ __forceinline__ void barrier_lds() {
  asm volatile("s_waitcnt lgkmcnt(0)" ::: "memory");
  __builtin_amdgcn_s_barrier();
}

// ---------------- stage-1 perm tables ----------------
__global__ void build_tables1(int* __restrict__ piv1, int* __restrict__ kk1, int* __restrict__ kj1) {
  int t = threadIdx.x;
  if (t < NF1) {
    int i = t;
    int base = 0;
    for (int ii = 0; ii < i; ++ii) base += (NF1 - ii) + (NCPF1 - 1) * (NF1 - 1 - ii);
    int count = base;
    for (int j = 0; j < NCPF1; ++j) {
      int k0 = (j == 0) ? i : (i + 1);
      for (int k = k0; k < NF1; ++k) {
        piv1[count] = i * NCPF1 + j;
        kk1[count] = k;
        kj1[count] = k * NCPF1 + j;
        ++count;
      }
    }
  }
}

// ---------------- stage-2 j-major order tables ----------------
// gPkS[newg] = pivslot | kjslot<<5 | filter<<10 ; ktsC[kt*NS+q] = chan | ic<<10
__global__ void build_perm2(int* __restrict__ gmap, ushort* __restrict__ gPkS, uint* __restrict__ ktsC) {
  int t = threadIdx.x;
  if (t >= NKT2) return;
  int chans[NS];
  int nch = 0;
  int pivs[32], kjs[32];
  int base = t * 32;
  for (int u = 0; u < 32; ++u) {
    int g = base + u;
    if (g >= G2) { pivs[u] = -1; kjs[u] = -1; gmap[g] = -1; gPkS[g] = 0; continue; }
    int i, j, k;
    if (g < 21) {
      j = 0; int r = g; i = 0; int len = 6;
      while (r >= len) { r -= len; ++i; len = 6 - i; }
      k = i + r;
    } else {
      int gp = g - 21; j = 1 + gp / 15; int r = gp % 15; i = 0; int len = 5;
      while (r >= len) { r -= len; ++i; len = 5 - i; }
      k = i + 1 + r;
    }
    pivs[u] = i * 100 + j; kjs[u] = k * 100 + j;
    int ob = (i == 0) ? 0 : (i == 1) ? 501 : (i == 2) ? 902 : (i == 3) ? 1203 : (i == 4) ? 1404 : 1505;
    int old;
    if (j == 0) old = ob + (k - i);
    else old = ob + (6 - i) + (j - 1) * (5 - i) + (k - i - 1);
    gmap[g] = old;
  }
  for (int u = 0; u < 32; ++u) {
    int g = base + u;
    if (g >= G2) continue;
    int ps = -1, ks2 = -1;
    for (int q = 0; q < nch; ++q) {
      if (chans[q] == pivs[u]) ps = q;
      if (chans[q] == kjs[u]) ks2 = q;
    }
    if (ps < 0) { ps = nch; chans[nch++] = pivs[u]; }
    if (ks2 < 0) { ks2 = nch; chans[nch++] = kjs[u]; }
    int f = kjs[u] / 100;
    gPkS[g] = (ushort)(ps | (ks2 << 5) | (f << 10));
  }
  for (int q = 0; q < NS; ++q) {
    int ch = (q < nch) ? chans[q] : 0;
    ktsC[t * NS + q] = (uint)ch | ((uint)(ch / 6) << 10);
  }
}

// column-permute pw2 weights into single RNE bf16 plane [320][1536]
__global__ __launch_bounds__(256) void prep_w2(const float* __restrict__ pw2w, const int* __restrict__ gmap,
                                               ushort* __restrict__ whi) {
  int idx = blockIdx.x * 256 + threadIdx.x;
  if (idx >= 320 * KTOT) return;
  int oc = idx / KTOT, k = idx % KTOT;
  int old = gmap[k];
  float v = (oc < 300 && old >= 0) ? pw2w[oc * G2 + old] : 0.f;
  whi[idx] = rne_bf16(v);
}

// split pw1 weights -> bf16 hi/lo [128][160]
__global__ __launch_bounds__(256) void prep_w1(const float* __restrict__ pw1w, ushort* __restrict__ p1h,
                                               ushort* __restrict__ p1l) {
  int idx = blockIdx.x * 256 + threadIdx.x;
  if (idx >= 128 * 160) return;
  int oc = idx / 160, k = idx % 160;
  float v = (oc < 100 && k < G1) ? pw1w[oc * G1 + k] : 0.f;
  ushort h, l;
  bsplit(v, h, l);
  p1h[idx] = h;
  p1l[idx] = l;
}

// pack dw2 weights [600][12]
__global__ __launch_bounds__(256) void prep_dw2(const float* __restrict__ dw2w, const float* __restrict__ dw2b,
                                                float* __restrict__ dw2p) {
  int c = blockIdx.x * 256 + threadIdx.x;
  if (c >= 600) return;
  for (int q = 0; q < 9; ++q) dw2p[c * 12 + q] = dw2w[c * 9 + q];
  dw2p[c * 12 + 9] = dw2b[c];
  dw2p[c * 12 + 10] = 0.f;
  dw2p[c * 12 + 11] = 0.f;
}

// combined filter-sum stencil: wcomb[6][18][9], bcomb[6]
__global__ void prep_wcomb(const float* __restrict__ dw2w, const float* __restrict__ dw2b,
                           float* __restrict__ wcomb, float* __restrict__ bcomb) {
  int idx = threadIdx.x + blockIdx.x * 256;
  if (idx < 6 * 18 * 9) {
    int f = idx / 162, s = (idx % 162) / 9, tap = idx % 9;
    int ic = (f * 100) / 6 + s;
    int clo = f * 100, chi = f * 100 + 100;
    int ilo = ic * 6, ihi = ic * 6 + 6;
    int lo = clo > ilo ? clo : ilo;
    int hi = chi < ihi ? chi : ihi;
    float sacc = 0.f;
    for (int c = lo; c < hi; ++c) sacc += dw2w[c * 9 + tap];
    wcomb[idx] = sacc;
  }
  if (idx < 6) {
    float sacc = 0.f;
    for (int m = 0; m < 100; ++m) sacc += dw2b[idx * 100 + m];
    bcomb[idx] = sacc;
  }
}

// ---------------- stage 1 (proven): dwconv1 + perm1 + pw1 via MFMA + in-lane pool ----------------
__global__ __launch_bounds__(256) void stage1f(const float* __restrict__ x, const float* __restrict__ dw1w,
                                               const float* __restrict__ dw1b, const ushort* __restrict__ p1h,
                                               const ushort* __restrict__ p1l, const float* __restrict__ pw1b,
                                               const int* __restrict__ piv, const int* __restrict__ kk,
                                               const int* __restrict__ kj, ushort* __restrict__ h1) {
  __shared__ float xs[3][4][34];
  __shared__ float ys[30][64];
  __shared__ float Ss[NF1][64];
  __shared__ ushort g[64][168];
  __shared__ uint tbl[G1];

  int b = blockIdx.x >> 4;
  int oh = blockIdx.x & 15;
  int t = threadIdx.x;
  int lane = t & 63, wave = t >> 6;
  int lrow = lane & 15, lkk = lane >> 4;

  if (t < G1) tbl[t] = (uint)piv[t] | ((uint)kj[t] << 8) | ((uint)kk[t] << 16);
  for (int idx = t; idx < 3 * 4 * 34; idx += 256) {
    int c = idx / 136, rem = idx % 136;
    int r = rem / 34, cc = rem % 34;
    int row = 2 * oh - 1 + r, col = cc - 1;
    float v = 0.f;
    if (row >= 0 && row < 32 && col >= 0 && col < 32) v = x[(((size_t)b * 3 + c) * 32 + row) * 32 + col];
    xs[c][r][cc] = v;
  }
  __syncthreads();
  for (int idx = t; idx < 30 * 64; idx += 256) {
    int c = idx >> 6, p = idx & 63;
    int rr = p >> 5, w = p & 31;
    int ic = c / 10;
    float acc = dw1b[c];
#pragma unroll
    for (int kh = 0; kh < 3; ++kh)
#pragma unroll
      for (int kw = 0; kw < 3; ++kw) acc += xs[ic][rr + kh][w + kw] * dw1w[c * 9 + kh * 3 + kw];
    ys[c][p] = acc;
  }
  __syncthreads();
  for (int idx = t; idx < NF1 * 64; idx += 256) {
    int f = idx >> 6, p = idx & 63;
    Ss[f][p] = ys[3 * f][p] + ys[3 * f + 1][p] + ys[3 * f + 2][p];
  }
  __syncthreads();
  {
    int n = t >> 2, qd = t & 3;
    int sub = n >> 4, ow = n & 15;
    int px = 32 * (sub >> 1) + 2 * ow + (sub & 1);
#pragma unroll
    for (int pass = 0; pass < 10; ++pass) {
      int k0 = pass * 16 + qd * 4;
      union { ushort us[4]; unsigned long long v; } pv;
#pragma unroll
      for (int c = 0; c < 4; ++c) {
        int k = k0 + c;
        float val = 0.f;
        if (k < G1) {
          uint tb = tbl[k];
          val = fmaxf(ys[(tb & 255)][px] + Ss[(tb >> 16)][px] - ys[((tb >> 8) & 255)][px], 0.f);
        }
        pv.us[c] = rne_bf16(val);
      }
      *(unsigned long long*)&g[n][k0] = pv.v;
    }
  }
  __syncthreads();
  f32x4 acc[2][4];
#pragma unroll
  for (int mt = 0; mt < 2; ++mt)
#pragma unroll
    for (int nt = 0; nt < 4; ++nt) acc[mt][nt] = (f32x4){0.f, 0.f, 0.f, 0.f};
#pragma unroll
  for (int ks = 0; ks < 5; ++ks) {
    int koff = ks * 32 + lkk * 8;
    bf16x8 Bh[4];
#pragma unroll
    for (int nt = 0; nt < 4; ++nt) Bh[nt] = *(const bf16x8*)&g[nt * 16 + lrow][koff];
#pragma unroll
    for (int mt = 0; mt < 2; ++mt) {
      int row = wave * 32 + mt * 16 + lrow;
      bf16x8 Ah = *(const bf16x8*)(p1h + row * 160 + koff);
      bf16x8 Al = *(const bf16x8*)(p1l + row * 160 + koff);
#pragma unroll
      for (int nt = 0; nt < 4; ++nt) {
        f32x4 c = acc[mt][nt];
        c = __builtin_amdgcn_mfma_f32_16x16x32_bf16(Ah, Bh[nt], c, 0, 0, 0);
        c = __builtin_amdgcn_mfma_f32_16x16x32_bf16(Al, Bh[nt], c, 0, 0, 0);
        acc[mt][nt] = c;
      }
    }
  }
#pragma unroll
  for (int mt = 0; mt < 2; ++mt) {
#pragma unroll
    for (int r = 0; r < 4; ++r) {
      int oc = wave * 32 + mt * 16 + lkk * 4 + r;
      if (oc < 100) {
        float v = fmaxf(fmaxf(acc[mt][0][r], acc[mt][1][r]), fmaxf(acc[mt][2][r], acc[mt][3][r]));
        float h = fmaxf(v + pw1b[oc], 0.f);
        h1[((size_t)b * 100 + oc) * 256 + oh * 16 + lrow] = rne_bf16(h);
      }
    }
  }
}

// ---------------- stage 2 v19: N=128 half-image tiles, single-term W (no spill) ----------------
// block = (b, half q). 8 waves: 4 producers (C1 slots + C2), 4 consumers acc[5][8] + Ah[5].
// LDS: h1s[100][10][20]u16 @0 (40000) | y2c[2][20][130]f32 @40000 (20800) | G 2x128x80B @60800 (20480)
//      Slp[6][132]f32 @81280 (3168) | gPk u16[1536] @84448 (3072) | kts u32[960] @87520 (3840) = 91360
__global__ __launch_bounds__(512, 2) void stage2f(
    const ushort* __restrict__ h1, const ushort* __restrict__ whi,
    const float* __restrict__ dw2p, const float* __restrict__ wcomb, const float* __restrict__ bcomb,
    const float* __restrict__ pw2b, const ushort* __restrict__ gPkS, const uint* __restrict__ ktsC,
    ushort* __restrict__ h2) {
  extern __shared__ char sm[];
  ushort* h1s = (ushort*)sm;
  float* y2c = (float*)(sm + 40000);
  char* Ghb = sm + 60800;
  float* Slp = (float*)(sm + 81280);
  ushort* gPk = (ushort*)(sm + 84448);
  uint* kts = (uint*)(sm + 87520);

  int blk = blockIdx.x;
  int b = blk >> 1, q = blk & 1;  // half q: pre-pool rows 8q..8q+7
  int t = threadIdx.x;
  int lane = t & 63, wave = t >> 6;
  int lrow = lane & 15, lkk = lane >> 4;

  for (int i = t; i < 768; i += 512) ((uint*)gPk)[i] = ((const uint*)gPkS)[i];
  for (int i = t; i < NKT2 * NS; i += 512) kts[i] = ktsC[i];
  for (int i = t; i < 10000; i += 512) ((uint*)h1s)[i] = 0u;
  __syncthreads();
  const ushort* hb = h1 + (size_t)b * 25600;
  for (int i = t; i < 1000; i += 512) {
    int ic = i / 10, rr = i % 10;
    int hr = 8 * q - 1 + rr;
    if (hr >= 0 && hr < 16) {
      const ushort* src = hb + ic * 256 + hr * 16;
      ushort* dst = &h1s[(ic * 10 + rr) * 20 + 1];
#pragma unroll
      for (int c2 = 0; c2 < 16; ++c2) dst[c2] = src[c2];
    }
  }
  __syncthreads();
  // filter sums S (f32) for this half's 128 pixels
  for (int i = t; i < 6 * 128; i += 512) {
    int f = i >> 7, p = i & 127;
    int r = p >> 4, w = p & 15;
    int iclo = (f * 100) / 6;
    float s = bcomb[f];
    for (int ss2 = 0; ss2 < 18; ++ss2) {
      int ic = iclo + ss2;
      if (ic > 99) ic = 99;
      const float* wv = wcomb + (f * 18 + ss2) * 9;
#pragma unroll
      for (int dh = 0; dh < 3; ++dh)
#pragma unroll
        for (int dw = 0; dw < 3; ++dw)
          s += wv[dh * 3 + dw] * bf_to_f(h1s[(ic * 10 + r + dh) * 20 + w + dw]);
    }
    Slp[f * 132 + p] = s;
  }
  __syncthreads();

  if (wave < 4) {
    // ===== PRODUCERS (t<256): C1 slots (tile s, pass0 prefetched) + C2 (tile s-1) =====
    int n = t & 127, kg = t >> 7;  // C2: pixel n, k-group kg (16 k's)
    int slot0 = t >> 4, rem0 = t & 15, r0 = rem0 >> 1, half0 = rem0 & 1;  // C1 pass-0 task
    uint ktN = kts[slot0];  // tile 0
    const float4* wpN = (const float4*)(dw2p + (ktN & 1023) * 12);
    float4 waN = wpN[0], wbN = wpN[1], wcN = wpN[2];
    uint4 pkN0 = {0, 0, 0, 0}, pkN1 = {0, 0, 0, 0};
    for (int s = 0; s <= NKT2 + 1; ++s) {
      uint ktC = ktN;
      float4 waC = waN, wbC = wbN, wcC = wcN;
      uint4 pkC0 = pkN0, pkC1 = pkN1;
      if (s < NKT2) {
        pkN0 = *(const uint4*)&gPk[s * 32 + kg * 16];
        pkN1 = *(const uint4*)&gPk[s * 32 + kg * 16 + 8];
      }
      if (s + 1 < NKT2) {
        ktN = kts[(s + 1) * NS + slot0];
        const float4* wp4 = (const float4*)(dw2p + (ktN & 1023) * 12);
        waN = wp4[0]; wbN = wp4[1]; wcN = wp4[2];
      }
      // C2: G build for tile s-1
      if (s >= 1 && s <= NKT2) {
        int bc = (s - 1) & 1;
        char* gb = Ghb + bc * 10240;
#pragma unroll
        for (int h = 0; h < 2; ++h) {
          uint w4[4] = {h ? pkC1.x : pkC0.x, h ? pkC1.y : pkC0.y,
                        h ? pkC1.z : pkC0.z, h ? pkC1.w : pkC0.w};
          union { ushort us[8]; bf16x8 v; } ph;
#pragma unroll
          for (int c = 0; c < 8; ++c) {
            uint pk = (w4[c >> 1] >> ((c & 1) * 16)) & 0xffffu;
            int ps = pk & 31, ks = (pk >> 5) & 31, f = (pk >> 10) & 7;
            float v = fmaxf(y2c[bc * 2600 + ps * 130 + n] + Slp[f * 132 + n] -
                            y2c[bc * 2600 + ks * 130 + n], 0.f);
            ph.us[c] = rne_bf16(v);
          }
          int oct = kg * 2 + h;
          uint off = (uint)n * 80u + (uint)((oct ^ (n & 3)) * 16);
          *(bf16x8*)(gb + off) = ph.v;
        }
      }
      // C1: dwconv2 slots for tile s (320 tasks); pass0 uses prefetched weights
      if (s < NKT2) {
        {
          int ic = (ktC >> 10) & 127;
          int w0 = half0 * 8;
          float fr[3][10];
#pragma unroll
          for (int dr = 0; dr < 3; ++dr)
#pragma unroll
            for (int cc = 0; cc < 10; ++cc)
              fr[dr][cc] = bf_to_f(h1s[(ic * 10 + r0 + dr) * 20 + w0 + cc]);
          float* dst = &y2c[(s & 1) * 2600 + slot0 * 130 + r0 * 16 + w0];
#pragma unroll
          for (int w = 0; w < 8; ++w) {
            float sa = wcC.y;
            sa += fr[0][w] * waC.x + fr[0][w + 1] * waC.y + fr[0][w + 2] * waC.z;
            sa += fr[1][w] * waC.w + fr[1][w + 1] * wbC.x + fr[1][w + 2] * wbC.y;
            sa += fr[2][w] * wbC.z + fr[2][w + 1] * wbC.w + fr[2][w + 2] * wcC.x;
            dst[w] = sa;
          }
        }
        if (t < 64) {  // pass 1: tasks 256..319
          int task = 256 + t;
          int slot = task >> 4, rem = task & 15, r = rem >> 1, half = rem & 1;
          uint ci = kts[s * NS + slot];
          int chan = ci & 1023, ic = (ci >> 10) & 127;
          const float4* wp4 = (const float4*)(dw2p + chan * 12);
          float4 wa = wp4[0], wb4 = wp4[1], wc4 = wp4[2];
          int w0 = half * 8;
          float fr[3][10];
#pragma unroll
          for (int dr = 0; dr < 3; ++dr)
#pragma unroll
            for (int cc = 0; cc < 10; ++cc)
              fr[dr][cc] = bf_to_f(h1s[(ic * 10 + r + dr) * 20 + w0 + cc]);
          float* dst = &y2c[(s & 1) * 2600 + slot * 130 + r * 16 + w0];
#pragma unroll
          for (int w = 0; w < 8; ++w) {
            float sa = wc4.y;
            sa += fr[0][w] * wa.x + fr[0][w + 1] * wa.y + fr[0][w + 2] * wa.z;
            sa += fr[1][w] * wa.w + fr[1][w + 1] * wb4.x + fr[1][w + 2] * wb4.y;
            sa += fr[2][w] * wb4.z + fr[2][w + 1] * wb4.w + fr[2][w + 2] * wc4.x;
            dst[w] = sa;
          }
        }
      }
      barrier_lds();
    }
  } else {
    // ===== CONSUMERS: MFMA tile s-2 (A regs from phase s-1, B in-phase from LDS) =====
    int cw = wave - 4;  // 0..3 -> 80 oc rows each
    f32x4 acc[5][8];
#pragma unroll
    for (int mt = 0; mt < 5; ++mt)
#pragma unroll
      for (int nt = 0; nt < 8; ++nt) acc[mt][nt] = (f32x4){0.f, 0.f, 0.f, 0.f};
    bf16x8 Ah[5];

    for (int s = 0; s <= NKT2 + 1; ++s) {
      if (s >= 2) {
        int bm = (s - 2) & 1;
        const char* gb = Ghb + bm * 10240;
        __builtin_amdgcn_s_setprio(1);
#pragma unroll
        for (int nt = 0; nt < 8; ++nt) {
          int n2 = nt * 16 + lrow;
          uint off = (uint)n2 * 80u + (uint)((lkk ^ (n2 & 3)) * 16);
          bf16x8 Bh = *(const bf16x8*)(gb + off);
#pragma unroll
          for (int mt = 0; mt < 5; ++mt)
            acc[mt][nt] = __builtin_amdgcn_mfma_f32_16x16x32_bf16(Ah[mt], Bh, acc[mt][nt], 0, 0, 0);
        }
        __builtin_amdgcn_s_setprio(0);
      }
      int ka = s - 1;
      if (ka >= 0 && ka < NKT2) {
        const size_t wof = (size_t)(cw * 80 + lrow) * KTOT + (size_t)ka * 32 + (size_t)lkk * 8;
#pragma unroll
        for (int mt = 0; mt < 5; ++mt)
          Ah[mt] = *(const bf16x8*)(whi + wof + (size_t)mt * 16 * KTOT);
      }
      barrier_lds();
    }

    // epilogue: pool rows (nt pairs) + cols (lane shuffle), bias, relu, bf16 store
#pragma unroll
    for (int mt = 0; mt < 5; ++mt) {
      int ocb = cw * 80 + mt * 16 + lkk * 4;
#pragma unroll
      for (int p = 0; p < 4; ++p) {
#pragma unroll
        for (int r = 0; r < 4; ++r) {
          float v = fmaxf(acc[mt][2 * p][r], acc[mt][2 * p + 1][r]);
          float v2 = fmaxf(v, __shfl_xor(v, 1));
          int oc = ocb + r;
          if ((lane & 1) == 0 && oc < 300) {
            float o = fmaxf(v2 + pw2b[oc], 0.f);
            h2[((size_t)b * 300 + oc) * 64 + (q * 4 + p) * 8 + (lrow >> 1)] = rne_bf16(o);
          }
        }
      }
    }
  }
}

// ---------------- FC (folded fc2@fc1) ----------------
__global__ __launch_bounds__(256) void fold_fc(const float* __restrict__ fc1w, const float* __restrict__ fc2w,
                                               float* __restrict__ combW) {
  int idx = blockIdx.x * 256 + threadIdx.x;
  if (idx >= 10 * 19200) return;
  int o = idx / 19200, c = idx % 19200;
  float s = 0.f;
  for (int m = 0; m < 120; ++m) s += fc2w[o * 120 + m] * fc1w[m * 19200 + c];
  combW[idx] = s;
}

__global__ void fold_b(const float* __restrict__ fc1b, const float* __restrict__ fc2w,
                       const float* __restrict__ fc2b, float* __restrict__ combB) {
  int o = threadIdx.x;
  if (o < 10) {
    float s = fc2b[o];
    for (int m = 0; m < 120; ++m) s += fc2w[o * 120 + m] * fc1b[m];
    combB[o] = s;
  }
}

__global__ __launch_bounds__(256) void fc_out(const ushort* __restrict__ h2, const float* __restrict__ combW,
                                              const float* __restrict__ combB, float* __restrict__ out, int b0) {
  int b = blockIdx.x / 10, o = blockIdx.x % 10;
  const ushort* hp = h2 + (size_t)b * 19200;
  const float* wp = combW + (size_t)o * 19200;
  float s = 0.f;
  for (int idx = threadIdx.x; idx < 2400; idx += 256) {
    bf16x8 hv = *(const bf16x8*)(hp + idx * 8);
    float4 w0 = *(const float4*)(wp + idx * 8);
    float4 w1 = *(const float4*)(wp + idx * 8 + 4);
    s += bf_to_f((ushort)hv[0]) * w0.x + bf_to_f((ushort)hv[1]) * w0.y;
    s += bf_to_f((ushort)hv[2]) * w0.z + bf_to_f((ushort)hv[3]) * w0.w;
    s += bf_to_f((ushort)hv[4]) * w1.x + bf_to_f((ushort)hv[5]) * w1.y;
    s += bf_to_f((ushort)hv[6]) * w1.z + bf_to_f((ushort)hv[7]) * w1.w;
  }
  __shared__ float red[256];
  red[threadIdx.x] = s;
  __syncthreads();
  for (int stride = 128; stride > 0; stride >>= 1) {
    if (threadIdx.x < stride) red[threadIdx.x] += red[threadIdx.x + stride];
    __syncthreads();
  }
  if (threadIdx.x == 0) out[(size_t)(b0 + b) * 10 + o] = red[0] + combB[o];
}

extern "C" void kernel_launch(void* const* d_in, const int* in_sizes, int n_in,
                              void* d_out, int out_size, void* d_ws, size_t ws_size,
                              hipStream_t stream) {
  const float* x = (const float*)d_in[0];
  const float* dw1w = (const float*)d_in[1];
  const float* dw1b = (const float*)d_in[2];
  const float* pw1w = (const float*)d_in[3];
  const float* pw1b = (const float*)d_in[4];
  const float* dw2w = (const float*)d_in[5];
  const float* dw2b = (const float*)d_in[6];
  const float* pw2w = (const float*)d_in[7];
  const float* pw2b = (const float*)d_in[8];
  const float* fc1w = (const float*)d_in[9];
  const float* fc1b = (const float*)d_in[10];
  const float* fc2w = (const float*)d_in[11];
  const float* fc2b = (const float*)d_in[12];
  float* out = (float*)d_out;

  char* ws = (char*)d_ws;
  size_t off = 0;
  auto alloc = [&](size_t bytes) -> void* {
    off = (off + 255) & ~(size_t)255;
    void* p = ws + off;
    off += bytes;
    return p;
  };
  int* piv1 = (int*)alloc(G1 * 4);
  int* kk1 = (int*)alloc(G1 * 4);
  int* kj1 = (int*)alloc(G1 * 4);
  int* gmap = (int*)alloc(KTOT * 4);
  ushort* gPkS = (ushort*)alloc(KTOT * 2);
  uint* ktsC = (uint*)alloc(NKT2 * NS * 4);
  float* combW = (float*)alloc((size_t)10 * 19200 * 4);
  float* combB = (float*)alloc(16 * 4);
  ushort* whi = (ushort*)alloc((size_t)320 * KTOT * 2);
  ushort* p1h = (ushort*)alloc((size_t)128 * 160 * 2);
  ushort* p1l = (ushort*)alloc((size_t)128 * 160 * 2);
  float* dw2p = (float*)alloc((size_t)600 * 12 * 4);
  float* wcombp = (float*)alloc((size_t)6 * 18 * 9 * 4);
  float* bcombp = (float*)alloc(8 * 4);
  size_t static_end = (off + 255) & ~(size_t)255;

  size_t per_img = 51200 + 38400;
  long long avail = (long long)ws_size - (long long)static_end - 4096;
  int CB = 1;
  if (avail > 0) {
    long long c = avail / (long long)(per_img + 512);
    if (c > 500) c = 500;
    if (c < 1) c = 1;
    CB = (int)c;
  }
  ushort* h1 = (ushort*)alloc((size_t)CB * 25600 * 2);
  ushort* h2 = (ushort*)alloc((size_t)CB * 19200 * 2);

  const uint SMEM2 = 91360;
  hipFuncSetAttribute((const void*)stage2f, hipFuncAttributeMaxDynamicSharedMemorySize, (int)SMEM2);

  build_tables1<<<1, 64, 0, stream>>>(piv1, kk1, kj1);
  build_perm2<<<1, 64, 0, stream>>>(gmap, gPkS, ktsC);
  prep_dw2<<<3, 256, 0, stream>>>(dw2w, dw2b, dw2p);
  prep_wcomb<<<4, 256, 0, stream>>>(dw2w, dw2b, wcombp, bcombp);
  prep_w2<<<(320 * KTOT + 255) / 256, 256, 0, stream>>>(pw2w, gmap, whi);
  prep_w1<<<(128 * 160 + 255) / 256, 256, 0, stream>>>(pw1w, p1h, p1l);
  fold_fc<<<(10 * 19200 + 255) / 256, 256, 0, stream>>>(fc1w, fc2w, combW);
  fold_b<<<1, 64, 0, stream>>>(fc1b, fc2w, fc2b, combB);

  for (int b0 = 0; b0 < 500; b0 += CB) {
    int nb = 500 - b0 < CB ? 500 - b0 : CB;
    stage1f<<<nb * 16, 256, 0, stream>>>(x + (size_t)b0 * 3 * 1024, dw1w, dw1b, p1h, p1l, pw1b,
                                         piv1, kk1, kj1, h1);
    stage2f<<<nb * 2, 512, SMEM2, stream>>>(h1, whi, dw2p, wcombp, bcombp, pw2b,
                                            gPkS, ktsC, h2);
    fc_out<<<nb * 10, 256, 0, stream>>>(h2, combW, combB, out, b0);
  }
}

// Round 20
// 553.924 us; speedup vs baseline: 1.4715x; 1.3972x over previous
//
#include <hip/hip_runtime.h>

#define NF1 10
#define NCPF1 3
#define G1 145
#define G2 1506
#define KTOT 1536
#define NKT2 48
#define NS 20  // max distinct channels (slots) per 32-group k-tile, j-major order

typedef __attribute__((ext_vector_type(8))) short bf16x8;
typedef __attribute__((ext_vector_type(4))) float f32x4;

__device__ __forceinline__ ushort rne_bf16(float v) {
  union { float f; uint u; } a; a.f = v;
  return (ushort)((a.u + 0x7fffu + ((a.u >> 16) & 1u)) >> 16);
}
__device__ __forceinline__ float bf_to_f(ushort s) {
  union { uint u; float f; } a; a.u = ((uint)s) << 16;
  return a.f;
}
__device__ __forceinline__ void bsplit(float v, ushort& h, ushort& l) {
  union { float f; uint u; } a; a.f = v;
  uint hu = (a.u + 0x7fffu + ((a.u >> 16) & 1u)) >> 16;
  union { uint u; float f; } hf; hf.u = hu << 16;
  union { float f; uint u; } b2; b2.f = v - hf.f;
  h = (ushort)hu;
  l = (ushort)((b2.u + 0x7fffu + ((b2.u >> 16) & 1u)) >> 16);
}

// LDS-only barrier: drains lgkmcnt, leaves global loads in flight.
__device__ __forceinline__ void barrier_lds() {
  asm volatile("s_waitcnt lgkmcnt(0)" ::: "memory");
  __builtin_amdgcn_s_barrier();
}

// ---------------- stage-1 perm tables ----------------
__global__ void build_tables1(int* __restrict__ piv1, int* __restrict__ kk1, int* __restrict__ kj1) {
  int t = threadIdx.x;
  if (t < NF1) {
    int i = t;
    int base = 0;
    for (int ii = 0; ii < i; ++ii) base += (NF1 - ii) + (NCPF1 - 1) * (NF1 - 1 - ii);
    int count = base;
    for (int j = 0; j < NCPF1; ++j) {
      int k0 = (j == 0) ? i : (i + 1);
      for (int k = k0; k < NF1; ++k) {
        piv1[count] = i * NCPF1 + j;
        kk1[count] = k;
        kj1[count] = k * NCPF1 + j;
        ++count;
      }
    }
  }
}

// ---------------- stage-2 j-major order tables ----------------
// gPkS[newg] = pivslot | kjslot<<5 | filter<<10 ; ktsC[kt*NS+q] = chan | ic<<10
__global__ void build_perm2(int* __restrict__ gmap, ushort* __restrict__ gPkS, uint* __restrict__ ktsC) {
  int t = threadIdx.x;
  if (t >= NKT2) return;
  int chans[NS];
  int nch = 0;
  int pivs[32], kjs[32];
  int base = t * 32;
  for (int u = 0; u < 32; ++u) {
    int g = base + u;
    if (g >= G2) { pivs[u] = -1; kjs[u] = -1; gmap[g] = -1; gPkS[g] = 0; continue; }
    int i, j, k;
    if (g < 21) {
      j = 0; int r = g; i = 0; int len = 6;
      while (r >= len) { r -= len; ++i; len = 6 - i; }
      k = i + r;
    } else {
      int gp = g - 21; j = 1 + gp / 15; int r = gp % 15; i = 0; int len = 5;
      while (r >= len) { r -= len; ++i; len = 5 - i; }
      k = i + 1 + r;
    }
    pivs[u] = i * 100 + j; kjs[u] = k * 100 + j;
    int ob = (i == 0) ? 0 : (i == 1) ? 501 : (i == 2) ? 902 : (i == 3) ? 1203 : (i == 4) ? 1404 : 1505;
    int old;
    if (j == 0) old = ob + (k - i);
    else old = ob + (6 - i) + (j - 1) * (5 - i) + (k - i - 1);
    gmap[g] = old;
  }
  for (int u = 0; u < 32; ++u) {
    int g = base + u;
    if (g >= G2) continue;
    int ps = -1, ks2 = -1;
    for (int q = 0; q < nch; ++q) {
      if (chans[q] == pivs[u]) ps = q;
      if (chans[q] == kjs[u]) ks2 = q;
    }
    if (ps < 0) { ps = nch; chans[nch++] = pivs[u]; }
    if (ks2 < 0) { ks2 = nch; chans[nch++] = kjs[u]; }
    int f = kjs[u] / 100;
    gPkS[g] = (ushort)(ps | (ks2 << 5) | (f << 10));
  }
  for (int q = 0; q < NS; ++q) {
    int ch = (q < nch) ? chans[q] : 0;
    ktsC[t * NS + q] = (uint)ch | ((uint)(ch / 6) << 10);
  }
}

// column-permute pw2 weights into single RNE bf16 plane [320][1536]
__global__ __launch_bounds__(256) void prep_w2(const float* __restrict__ pw2w, const int* __restrict__ gmap,
                                               ushort* __restrict__ whi) {
  int idx = blockIdx.x * 256 + threadIdx.x;
  if (idx >= 320 * KTOT) return;
  int oc = idx / KTOT, k = idx % KTOT;
  int old = gmap[k];
  float v = (oc < 300 && old >= 0) ? pw2w[oc * G2 + old] : 0.f;
  whi[idx] = rne_bf16(v);
}

// split pw1 weights -> bf16 hi/lo [128][160]
__global__ __launch_bounds__(256) void prep_w1(const float* __restrict__ pw1w, ushort* __restrict__ p1h,
                                               ushort* __restrict__ p1l) {
  int idx = blockIdx.x * 256 + threadIdx.x;
  if (idx >= 128 * 160) return;
  int oc = idx / 160, k = idx % 160;
  float v = (oc < 100 && k < G1) ? pw1w[oc * G1 + k] : 0.f;
  ushort h, l;
  bsplit(v, h, l);
  p1h[idx] = h;
  p1l[idx] = l;
}

// pack dw2 weights [600][12]
__global__ __launch_bounds__(256) void prep_dw2(const float* __restrict__ dw2w, const float* __restrict__ dw2b,
                                                float* __restrict__ dw2p) {
  int c = blockIdx.x * 256 + threadIdx.x;
  if (c >= 600) return;
  for (int q = 0; q < 9; ++q) dw2p[c * 12 + q] = dw2w[c * 9 + q];
  dw2p[c * 12 + 9] = dw2b[c];
  dw2p[c * 12 + 10] = 0.f;
  dw2p[c * 12 + 11] = 0.f;
}

// combined filter-sum stencil: wcomb[6][18][9], bcomb[6]
__global__ void prep_wcomb(const float* __restrict__ dw2w, const float* __restrict__ dw2b,
                           float* __restrict__ wcomb, float* __restrict__ bcomb) {
  int idx = threadIdx.x + blockIdx.x * 256;
  if (idx < 6 * 18 * 9) {
    int f = idx / 162, s = (idx % 162) / 9, tap = idx % 9;
    int ic = (f * 100) / 6 + s;
    int clo = f * 100, chi = f * 100 + 100;
    int ilo = ic * 6, ihi = ic * 6 + 6;
    int lo = clo > ilo ? clo : ilo;
    int hi = chi < ihi ? chi : ihi;
    float sacc = 0.f;
    for (int c = lo; c < hi; ++c) sacc += dw2w[c * 9 + tap];
    wcomb[idx] = sacc;
  }
  if (idx < 6) {
    float sacc = 0.f;
    for (int m = 0; m < 100; ++m) sacc += dw2b[idx * 100 + m];
    bcomb[idx] = sacc;
  }
}

// ---------------- stage 1 (proven): dwconv1 + perm1 + pw1 via MFMA + in-lane pool ----------------
__global__ __launch_bounds__(256) void stage1f(const float* __restrict__ x, const float* __restrict__ dw1w,
                                               const float* __restrict__ dw1b, const ushort* __restrict__ p1h,
                                               const ushort* __restrict__ p1l, const float* __restrict__ pw1b,
                                               const int* __restrict__ piv, const int* __restrict__ kk,
                                               const int* __restrict__ kj, ushort* __restrict__ h1) {
  __shared__ float xs[3][4][34];
  __shared__ float ys[30][64];
  __shared__ float Ss[NF1][64];
  __shared__ ushort g[64][168];
  __shared__ uint tbl[G1];

  int b = blockIdx.x >> 4;
  int oh = blockIdx.x & 15;
  int t = threadIdx.x;
  int lane = t & 63, wave = t >> 6;
  int lrow = lane & 15, lkk = lane >> 4;

  if (t < G1) tbl[t] = (uint)piv[t] | ((uint)kj[t] << 8) | ((uint)kk[t] << 16);
  for (int idx = t; idx < 3 * 4 * 34; idx += 256) {
    int c = idx / 136, rem = idx % 136;
    int r = rem / 34, cc = rem % 34;
    int row = 2 * oh - 1 + r, col = cc - 1;
    float v = 0.f;
    if (row >= 0 && row < 32 && col >= 0 && col < 32) v = x[(((size_t)b * 3 + c) * 32 + row) * 32 + col];
    xs[c][r][cc] = v;
  }
  __syncthreads();
  for (int idx = t; idx < 30 * 64; idx += 256) {
    int c = idx >> 6, p = idx & 63;
    int rr = p >> 5, w = p & 31;
    int ic = c / 10;
    float acc = dw1b[c];
#pragma unroll
    for (int kh = 0; kh < 3; ++kh)
#pragma unroll
      for (int kw = 0; kw < 3; ++kw) acc += xs[ic][rr + kh][w + kw] * dw1w[c * 9 + kh * 3 + kw];
    ys[c][p] = acc;
  }
  __syncthreads();
  for (int idx = t; idx < NF1 * 64; idx += 256) {
    int f = idx >> 6, p = idx & 63;
    Ss[f][p] = ys[3 * f][p] + ys[3 * f + 1][p] + ys[3 * f + 2][p];
  }
  __syncthreads();
  {
    int n = t >> 2, qd = t & 3;
    int sub = n >> 4, ow = n & 15;
    int px = 32 * (sub >> 1) + 2 * ow + (sub & 1);
#pragma unroll
    for (int pass = 0; pass < 10; ++pass) {
      int k0 = pass * 16 + qd * 4;
      union { ushort us[4]; unsigned long long v; } pv;
#pragma unroll
      for (int c = 0; c < 4; ++c) {
        int k = k0 + c;
        float val = 0.f;
        if (k < G1) {
          uint tb = tbl[k];
          val = fmaxf(ys[(tb & 255)][px] + Ss[(tb >> 16)][px] - ys[((tb >> 8) & 255)][px], 0.f);
        }
        pv.us[c] = rne_bf16(val);
      }
      *(unsigned long long*)&g[n][k0] = pv.v;
    }
  }
  __syncthreads();
  f32x4 acc[2][4];
#pragma unroll
  for (int mt = 0; mt < 2; ++mt)
#pragma unroll
    for (int nt = 0; nt < 4; ++nt) acc[mt][nt] = (f32x4){0.f, 0.f, 0.f, 0.f};
#pragma unroll
  for (int ks = 0; ks < 5; ++ks) {
    int koff = ks * 32 + lkk * 8;
    bf16x8 Bh[4];
#pragma unroll
    for (int nt = 0; nt < 4; ++nt) Bh[nt] = *(const bf16x8*)&g[nt * 16 + lrow][koff];
#pragma unroll
    for (int mt = 0; mt < 2; ++mt) {
      int row = wave * 32 + mt * 16 + lrow;
      bf16x8 Ah = *(const bf16x8*)(p1h + row * 160 + koff);
      bf16x8 Al = *(const bf16x8*)(p1l + row * 160 + koff);
#pragma unroll
      for (int nt = 0; nt < 4; ++nt) {
        f32x4 c = acc[mt][nt];
        c = __builtin_amdgcn_mfma_f32_16x16x32_bf16(Ah, Bh[nt], c, 0, 0, 0);
        c = __builtin_amdgcn_mfma_f32_16x16x32_bf16(Al, Bh[nt], c, 0, 0, 0);
        acc[mt][nt] = c;
      }
    }
  }
#pragma unroll
  for (int mt = 0; mt < 2; ++mt) {
#pragma unroll
    for (int r = 0; r < 4; ++r) {
      int oc = wave * 32 + mt * 16 + lkk * 4 + r;
      if (oc < 100) {
        float v = fmaxf(fmaxf(acc[mt][0][r], acc[mt][1][r]), fmaxf(acc[mt][2][r], acc[mt][3][r]));
        float h = fmaxf(v + pw1b[oc], 0.f);
        h1[((size_t)b * 100 + oc) * 256 + oh * 16 + lrow] = rne_bf16(h);
      }
    }
  }
}

// ---------------- stage 2 v20: N=64 slots skeleton + single-term W + (512,4) -> 2 blocks/CU ----------
// Regs/wave: acc[5][4]=80 AGPR + Ah[5]=20 + Bh batch 8 + ~15 misc ≈ 123 < 128.
// LDS ~52 KB -> 2 blocks/CU, 4 waves/SIMD. A keeps full-phase slack; B in-phase (2 batches).
__global__ __launch_bounds__(512, 4) void stage2f(
    const ushort* __restrict__ h1, const ushort* __restrict__ whi,
    const float* __restrict__ dw2p, const float* __restrict__ wcomb, const float* __restrict__ bcomb,
    const float* __restrict__ pw2b, const ushort* __restrict__ gPkS, const uint* __restrict__ ktsC,
    ushort* __restrict__ h2) {
  __shared__ ushort h1s[100][6][18];
  __shared__ float y2c[2][NS][72];
  __shared__ ushort Gh[2][64][40];
  __shared__ float Slp[6][72];
  __shared__ ushort gPk[KTOT];
  __shared__ uint kts[NKT2 * NS];

  int blk = blockIdx.x;
  int b = blk >> 2, q = blk & 3;
  int t = threadIdx.x;
  int lane = t & 63, wave = t >> 6;
  int lrow = lane & 15, lkk = lane >> 4;

  for (int i = t; i < KTOT / 2; i += 512) ((uint*)gPk)[i] = ((const uint*)gPkS)[i];
  for (int i = t; i < NKT2 * NS; i += 512) kts[i] = ktsC[i];
  for (int i = t; i < 5400; i += 512) ((uint*)h1s)[i] = 0u;
  __syncthreads();
  const ushort* hb = h1 + (size_t)b * 25600;
  for (int i = t; i < 600; i += 512) {
    int ic = i / 6, rr = i % 6;
    int hr = 4 * q - 1 + rr;
    if (hr >= 0 && hr < 16) {
      const ushort* src = hb + ic * 256 + hr * 16;
      ushort* dst = &h1s[ic][rr][1];
#pragma unroll
      for (int c2 = 0; c2 < 16; ++c2) dst[c2] = src[c2];
    }
  }
  __syncthreads();
  for (int i = t; i < 6 * 64; i += 512) {
    int f = i >> 6, p = i & 63;
    int r = p >> 4, w = p & 15;
    int iclo = (f * 100) / 6;
    float s = bcomb[f];
    for (int ss2 = 0; ss2 < 18; ++ss2) {
      int ic = iclo + ss2;
      if (ic > 99) ic = 99;
      const float* wv = wcomb + (f * 18 + ss2) * 9;
#pragma unroll
      for (int dh = 0; dh < 3; ++dh)
#pragma unroll
        for (int dw = 0; dw < 3; ++dw) s += wv[dh * 3 + dw] * bf_to_f(h1s[ic][r + dh][w + dw]);
    }
    Slp[f][p] = s;
  }
  __syncthreads();

  if (wave < 4) {
    // ===== PRODUCERS: C1 (tile s, tables prefetched) + C2 (tile s-1, pk prefetched) =====
    int n = t & 63;
    int koct = wave;
    bool doC1 = (t < 160);
    int slot = t >> 3, r = (t >> 1) & 3, half = t & 1;
    uint ktN = 0;
    float4 waN = {0, 0, 0, 0}, wbN = {0, 0, 0, 0}, wcN = {0, 0, 0, 0};
    if (doC1) {
      ktN = kts[slot];
      const float4* wp4 = (const float4*)(dw2p + (ktN & 1023) * 12);
      waN = wp4[0]; wbN = wp4[1]; wcN = wp4[2];
    }
    uint4 pkN = {0, 0, 0, 0};
    for (int s = 0; s <= NKT2 + 1; ++s) {
      uint ktC = ktN;
      float4 waC = waN, wbC = wbN, wcC = wcN;
      uint4 pkC = pkN;
      if (s < NKT2) pkN = *(const uint4*)&gPk[s * 32 + koct * 8];
      if (doC1 && s + 1 < NKT2) {
        ktN = kts[(s + 1) * NS + slot];
        const float4* wp4 = (const float4*)(dw2p + (ktN & 1023) * 12);
        waN = wp4[0]; wbN = wp4[1]; wcN = wp4[2];
      }
      // C2: G build for tile s-1 (single bf16 plane)
      if (s >= 1 && s <= NKT2) {
        int bc = (s - 1) & 1;
        union { ushort us[8]; bf16x8 v; } ph;
        uint pks[4] = {pkC.x, pkC.y, pkC.z, pkC.w};
#pragma unroll
        for (int c = 0; c < 8; ++c) {
          uint pk = (pks[c >> 1] >> ((c & 1) * 16)) & 0xffffu;
          int ps = pk & 31, ks = (pk >> 5) & 31, f = (pk >> 10) & 7;
          float v = fmaxf(y2c[bc][ps][n] + Slp[f][n] - y2c[bc][ks][n], 0.f);
          ph.us[c] = rne_bf16(v);
        }
        uint off = (uint)bc * 5120u + (uint)n * 80u + (uint)((koct ^ (n & 3)) * 16);
        *(bf16x8*)((char*)Gh + off) = ph.v;
      }
      // C1: dwconv2 for tile s (tables in regs)
      if (s < NKT2 && doC1) {
        int ic = (ktC >> 10) & 127;
        int w0 = half * 8;
        float fr[3][10];
#pragma unroll
        for (int dr = 0; dr < 3; ++dr)
#pragma unroll
          for (int cc = 0; cc < 10; ++cc) fr[dr][cc] = bf_to_f(h1s[ic][r + dr][w0 + cc]);
        float* dst = &y2c[s & 1][slot][r * 16 + w0];
#pragma unroll
        for (int w = 0; w < 8; ++w) {
          float sa = wcC.y;
          sa += fr[0][w] * waC.x + fr[0][w + 1] * waC.y + fr[0][w + 2] * waC.z;
          sa += fr[1][w] * waC.w + fr[1][w + 1] * wbC.x + fr[1][w + 2] * wbC.y;
          sa += fr[2][w] * wbC.z + fr[2][w + 1] * wbC.w + fr[2][w + 2] * wcC.x;
          dst[w] = sa;
        }
      }
      barrier_lds();
    }
  } else {
    // ===== CONSUMERS: MFMA tile s-2 (Ah regs from phase s-1, B in-phase 2x2 batches) =====
    int cw = wave - 4;
    f32x4 acc[5][4];
#pragma unroll
    for (int mt = 0; mt < 5; ++mt)
#pragma unroll
      for (int nt = 0; nt < 4; ++nt) acc[mt][nt] = (f32x4){0.f, 0.f, 0.f, 0.f};
    bf16x8 Ah[5];

    for (int s = 0; s <= NKT2 + 1; ++s) {
      int km = s - 2;
      if (km >= 0) {
        int bm = km & 1;
        const char* gb = (const char*)Gh + bm * 5120;
        __builtin_amdgcn_s_setprio(1);
#pragma unroll
        for (int half = 0; half < 2; ++half) {
          bf16x8 B0, B1;
          {
            int n0 = (half * 2) * 16 + lrow, n1 = (half * 2 + 1) * 16 + lrow;
            B0 = *(const bf16x8*)(gb + (uint)n0 * 80u + (uint)((lkk ^ (n0 & 3)) * 16));
            B1 = *(const bf16x8*)(gb + (uint)n1 * 80u + (uint)((lkk ^ (n1 & 3)) * 16));
          }
#pragma unroll
          for (int mt = 0; mt < 5; ++mt) {
            acc[mt][half * 2] =
                __builtin_amdgcn_mfma_f32_16x16x32_bf16(Ah[mt], B0, acc[mt][half * 2], 0, 0, 0);
            acc[mt][half * 2 + 1] =
                __builtin_amdgcn_mfma_f32_16x16x32_bf16(Ah[mt], B1, acc[mt][half * 2 + 1], 0, 0, 0);
          }
        }
        __builtin_amdgcn_s_setprio(0);
      }
      int ka = s - 1;
      if (ka >= 0 && ka < NKT2) {
        const size_t wof = (size_t)(cw * 80 + lrow) * KTOT + (size_t)ka * 32 + (size_t)lkk * 8;
#pragma unroll
        for (int mt = 0; mt < 5; ++mt)
          Ah[mt] = *(const bf16x8*)(whi + wof + (size_t)mt * 16 * KTOT);
      }
      barrier_lds();
    }

    // epilogue: 2x2 pool, bias, relu, bf16 store
#pragma unroll
    for (int mt = 0; mt < 5; ++mt) {
      int ocb = cw * 80 + mt * 16 + lkk * 4;
#pragma unroll
      for (int r = 0; r < 4; ++r) {
        float v01 = fmaxf(acc[mt][0][r], acc[mt][1][r]);
        float v23 = fmaxf(acc[mt][2][r], acc[mt][3][r]);
        v01 = fmaxf(v01, __shfl_xor(v01, 1));
        v23 = fmaxf(v23, __shfl_xor(v23, 1));
        int oc = ocb + r;
        if ((lane & 1) == 0 && oc < 300) {
          float b0 = pw2b[oc];
          size_t base = ((size_t)b * 300 + oc) * 64;
          h2[base + (q * 2 + 0) * 8 + (lrow >> 1)] = rne_bf16(fmaxf(v01 + b0, 0.f));
          h2[base + (q * 2 + 1) * 8 + (lrow >> 1)] = rne_bf16(fmaxf(v23 + b0, 0.f));
        }
      }
    }
  }
}

// ---------------- FC (folded fc2@fc1) ----------------
__global__ __launch_bounds__(256) void fold_fc(const float* __restrict__ fc1w, const float* __restrict__ fc2w,
                                               float* __restrict__ combW) {
  int idx = blockIdx.x * 256 + threadIdx.x;
  if (idx >= 10 * 19200) return;
  int o = idx / 19200, c = idx % 19200;
  float s = 0.f;
  for (int m = 0; m < 120; ++m) s += fc2w[o * 120 + m] * fc1w[m * 19200 + c];
  combW[idx] = s;
}

__global__ void fold_b(const float* __restrict__ fc1b, const float* __restrict__ fc2w,
                       const float* __restrict__ fc2b, float* __restrict__ combB) {
  int o = threadIdx.x;
  if (o < 10) {
    float s = fc2b[o];
    for (int m = 0; m < 120; ++m) s += fc2w[o * 120 + m] * fc1b[m];
    combB[o] = s;
  }
}

__global__ __launch_bounds__(256) void fc_out(const ushort* __restrict__ h2, const float* __restrict__ combW,
                                              const float* __restrict__ combB, float* __restrict__ out, int b0) {
  int b = blockIdx.x / 10, o = blockIdx.x % 10;
  const ushort* hp = h2 + (size_t)b * 19200;
  const float* wp = combW + (size_t)o * 19200;
  float s = 0.f;
  for (int idx = threadIdx.x; idx < 2400; idx += 256) {
    bf16x8 hv = *(const bf16x8*)(hp + idx * 8);
    float4 w0 = *(const float4*)(wp + idx * 8);
    float4 w1 = *(const float4*)(wp + idx * 8 + 4);
    s += bf_to_f((ushort)hv[0]) * w0.x + bf_to_f((ushort)hv[1]) * w0.y;
    s += bf_to_f((ushort)hv[2]) * w0.z + bf_to_f((ushort)hv[3]) * w0.w;
    s += bf_to_f((ushort)hv[4]) * w1.x + bf_to_f((ushort)hv[5]) * w1.y;
    s += bf_to_f((ushort)hv[6]) * w1.z + bf_to_f((ushort)hv[7]) * w1.w;
  }
  __shared__ float red[256];
  red[threadIdx.x] = s;
  __syncthreads();
  for (int stride = 128; stride > 0; stride >>= 1) {
    if (threadIdx.x < stride) red[threadIdx.x] += red[threadIdx.x + stride];
    __syncthreads();
  }
  if (threadIdx.x == 0) out[(size_t)(b0 + b) * 10 + o] = red[0] + combB[o];
}

extern "C" void kernel_launch(void* const* d_in, const int* in_sizes, int n_in,
                              void* d_out, int out_size, void* d_ws, size_t ws_size,
                              hipStream_t stream) {
  const float* x = (const float*)d_in[0];
  const float* dw1w = (const float*)d_in[1];
  const float* dw1b = (const float*)d_in[2];
  const float* pw1w = (const float*)d_in[3];
  const float* pw1b = (const float*)d_in[4];
  const float* dw2w = (const float*)d_in[5];
  const float* dw2b = (const float*)d_in[6];
  const float* pw2w = (const float*)d_in[7];
  const float* pw2b = (const float*)d_in[8];
  const float* fc1w = (const float*)d_in[9];
  const float* fc1b = (const float*)d_in[10];
  const float* fc2w = (const float*)d_in[11];
  const float* fc2b = (const float*)d_in[12];
  float* out = (float*)d_out;

  char* ws = (char*)d_ws;
  size_t off = 0;
  auto alloc = [&](size_t bytes) -> void* {
    off = (off + 255) & ~(size_t)255;
    void* p = ws + off;
    off += bytes;
    return p;
  };
  int* piv1 = (int*)alloc(G1 * 4);
  int* kk1 = (int*)alloc(G1 * 4);
  int* kj1 = (int*)alloc(G1 * 4);
  int* gmap = (int*)alloc(KTOT * 4);
  ushort* gPkS = (ushort*)alloc(KTOT * 2);
  uint* ktsC = (uint*)alloc(NKT2 * NS * 4);
  float* combW = (float*)alloc((size_t)10 * 19200 * 4);
  float* combB = (float*)alloc(16 * 4);
  ushort* whi = (ushort*)alloc((size_t)320 * KTOT * 2);
  ushort* p1h = (ushort*)alloc((size_t)128 * 160 * 2);
  ushort* p1l = (ushort*)alloc((size_t)128 * 160 * 2);
  float* dw2p = (float*)alloc((size_t)600 * 12 * 4);
  float* wcombp = (float*)alloc((size_t)6 * 18 * 9 * 4);
  float* bcombp = (float*)alloc(8 * 4);
  size_t static_end = (off + 255) & ~(size_t)255;

  size_t per_img = 51200 + 38400;
  long long avail = (long long)ws_size - (long long)static_end - 4096;
  int CB = 1;
  if (avail > 0) {
    long long c = avail / (long long)(per_img + 512);
    if (c > 500) c = 500;
    if (c < 1) c = 1;
    CB = (int)c;
  }
  ushort* h1 = (ushort*)alloc((size_t)CB * 25600 * 2);
  ushort* h2 = (ushort*)alloc((size_t)CB * 19200 * 2);

  build_tables1<<<1, 64, 0, stream>>>(piv1, kk1, kj1);
  build_perm2<<<1, 64, 0, stream>>>(gmap, gPkS, ktsC);
  prep_dw2<<<3, 256, 0, stream>>>(dw2w, dw2b, dw2p);
  prep_wcomb<<<4, 256, 0, stream>>>(dw2w, dw2b, wcombp, bcombp);
  prep_w2<<<(320 * KTOT + 255) / 256, 256, 0, stream>>>(pw2w, gmap, whi);
  prep_w1<<<(128 * 160 + 255) / 256, 256, 0, stream>>>(pw1w, p1h, p1l);
  fold_fc<<<(10 * 19200 + 255) / 256, 256, 0, stream>>>(fc1w, fc2w, combW);
  fold_b<<<1, 64, 0, stream>>>(fc1b, fc2w, fc2b, combB);

  for (int b0 = 0; b0 < 500; b0 += CB) {
    int nb = 500 - b0 < CB ? 500 - b0 : CB;
    stage1f<<<nb * 16, 256, 0, stream>>>(x + (size_t)b0 * 3 * 1024, dw1w, dw1b, p1h, p1l, pw1b,
                                         piv1, kk1, kj1, h1);
    stage2f<<<nb * 4, 512, 0, stream>>>(h1, whi, dw2p, wcombp, bcombp, pw2b,
                                        gPkS, ktsC, h2);
    fc_out<<<nb * 10, 256, 0, stream>>>(h2, combW, combB, out, b0);
  }
}